// Round 6
// baseline (439.788 us; speedup 1.0000x reference)
//
#include <hip/hip_runtime.h>

// LayerNorm(384) -> Linear(384->1536) -> exact GELU, fused via:
//   out[m,f] = rstd[m]*dot(x[m], gamma*W[f]) - (mean*rstd)[m]*s1[f] + s2[f]
// R3: K2 depth-3 prefetch pipeline — 4 LDS buffers, counted vmcnt (never 0
// mid-loop), lgkm-only end-of-step barriers + T2 XOR-swizzle on LDS tiles
// (inverse-swizzled global source, swizzled ds_read; involution).

#define M_DIM 50176
#define K_DIM 384
#define N_DIM 1536

typedef float f32x4 __attribute__((ext_vector_type(4)));
typedef short short8 __attribute__((ext_vector_type(8)));

#define OFF_WBF   0u
#define OFF_S1    1179648u                  // 1536*384*2
#define OFF_S2    1185792u
#define OFF_STATS 1191936u                  // float2 per row (rstd, mean*rstd)
#define OFF_XBF   1593344u                  // 50176*384 bf16
#define WS_FULL   (OFF_XBF + (size_t)M_DIM * K_DIM * 2)   // ~40.1 MB

__device__ __forceinline__ unsigned short f2bf(float f) {
    unsigned int u = __builtin_bit_cast(unsigned int, f);
    u += 0x7FFFu + ((u >> 16) & 1u);        // RNE
    return (unsigned short)(u >> 16);
}

__device__ __forceinline__ float gelu_tanh(float v) {
    float w = v * v;
    float a = v * (1.5957691f + 0.07135481f * w);
    float e = __expf(-a);
    return v * __builtin_amdgcn_rcpf(1.0f + e);
}

// ---------------- K0: fold gamma into W (bf16) + s1/s2 ----------------
__global__ __launch_bounds__(256) void foldW(
    const float* __restrict__ W, const float* __restrict__ gamma,
    const float* __restrict__ beta, const float* __restrict__ b,
    unsigned short* __restrict__ wbf, float* __restrict__ s1, float* __restrict__ s2)
{
    const int t = threadIdx.x, wv = t >> 6, ln = t & 63;
    const int f = blockIdx.x * 4 + wv;
    const float2* Wr = (const float2*)(W + (size_t)f * K_DIM);
    const float2* g2 = (const float2*)gamma;
    const float2* bt2 = (const float2*)beta;
    float sum1 = 0.f, sum2 = 0.f;
    unsigned int packed[3];
#pragma unroll
    for (int p = 0; p < 3; ++p) {
        int idx = p * 64 + ln;
        float2 w = Wr[idx]; float2 g = g2[idx]; float2 bt = bt2[idx];
        float w0 = w.x * g.x, w1 = w.y * g.y;
        sum1 += w0 + w1;
        sum2 += bt.x * w.x + bt.y * w.y;
        packed[p] = (unsigned int)f2bf(w0) | ((unsigned int)f2bf(w1) << 16);
    }
    unsigned int* wb = (unsigned int*)(wbf + (size_t)f * K_DIM);
#pragma unroll
    for (int p = 0; p < 3; ++p) wb[p * 64 + ln] = packed[p];
#pragma unroll
    for (int off = 32; off >= 1; off >>= 1) {
        sum1 += __shfl_xor(sum1, off);
        sum2 += __shfl_xor(sum2, off);
    }
    if (ln == 0) { s1[f] = sum1; s2[f] = b[f] + sum2; }
}

// ---------------- K1: per-row LN stats (+ optional x->bf16) ----------------
__global__ __launch_bounds__(256) void lnstats(
    const float* __restrict__ x, float2* __restrict__ stats,
    unsigned int* __restrict__ xbf, int do_conv)
{
    const int t = threadIdx.x, wv = t >> 6, ln = t & 63;
    const size_t r = (size_t)blockIdx.x * 4 + wv;
    const float2* xr = (const float2*)(x + r * K_DIM);
    float2 v[3];
    float s = 0.f, sq = 0.f;
#pragma unroll
    for (int p = 0; p < 3; ++p) {
        v[p] = xr[p * 64 + ln];
        s += v[p].x + v[p].y;
        sq += v[p].x * v[p].x + v[p].y * v[p].y;
    }
#pragma unroll
    for (int off = 32; off >= 1; off >>= 1) {
        s += __shfl_xor(s, off);
        sq += __shfl_xor(sq, off);
    }
    float mean = s * (1.0f / 384.0f);
    float var = sq * (1.0f / 384.0f) - mean * mean;
    float rstd = __builtin_amdgcn_rsqf(var + 1e-5f);
    if (ln == 0) stats[r] = make_float2(rstd, mean * rstd);
    if (do_conv) {
        unsigned int* xo = xbf + r * (K_DIM / 2);
#pragma unroll
        for (int p = 0; p < 3; ++p)
            xo[p * 64 + ln] = (unsigned int)f2bf(v[p].x) | ((unsigned int)f2bf(v[p].y) << 16);
    }
}

// ---------------- K2: 128x128 bf16 MFMA GEMM, depth-3 pipeline ----------------
// LDS tile layout: [128 rows][8 chunks of 16B]; stored chunk = c ^ (row&7)
// (T2 swizzle, involution). global_load_lds dest linear; SOURCE pre-swizzled.
#define NTILE (N_DIM / 128)                 // 12
#define NBLOCKS ((M_DIM / 128) * NTILE)     // 4704
#define NBUF 4

template<bool PRECONV>
__global__ __launch_bounds__(256) void gemm_ln_gelu(
    const unsigned short* __restrict__ xbf, const float* __restrict__ x,
    const unsigned short* __restrict__ wbf, const float2* __restrict__ stats,
    const float* __restrict__ s1, const float* __restrict__ s2,
    float* __restrict__ out)
{
    __shared__ short As[NBUF][128 * 64];    // 4 x 16 KB
    __shared__ short Bs[NBUF][128 * 64];    // 4 x 16 KB  (total 128 KB)
    const int t = threadIdx.x, wv = t >> 6, ln = t & 63;

    int raw = blockIdx.x;
    int bid = (raw & 7) * (NBLOCKS / 8) + (raw >> 3);   // XCD-chunked, bijective
    int mt = bid / NTILE, ntt = bid % NTILE;
    const size_t brow = (size_t)mt * 128;
    const int bcol = ntt * 128;
    const int wrow = (wv >> 1) * 64, wcol = (wv & 1) * 64;
    const int fr = ln & 15, cq = ln >> 4;   // frag row / 16B-chunk quarter

    auto stage = [&](int buf, int kt) {
        const int k0 = kt * 64;
#pragma unroll
        for (int i = 0; i < 4; ++i) {
            const int L = i * 4096 + t * 16;            // linear byte off in 16KB tile
            const int row = L >> 7;                     // /128B per row
            const int sc  = ((L >> 4) & 7) ^ (row & 7); // source chunk (involution)
            if (PRECONV) {
                const unsigned short* gpA = xbf + (size_t)(brow + row) * K_DIM + k0 + sc * 8;
                __builtin_amdgcn_global_load_lds(
                    (const __attribute__((address_space(1))) unsigned int*)gpA,
                    (__attribute__((address_space(3))) unsigned int*)((char*)&As[buf][0] + L),
                    16, 0, 0);
            } else {
                const float* gp = x + (size_t)(brow + row) * K_DIM + k0 + sc * 8;
                f32x4 u0 = *(const f32x4*)gp;
                f32x4 u1 = *(const f32x4*)(gp + 4);
                short8 h;
                h[0] = (short)f2bf(u0[0]); h[1] = (short)f2bf(u0[1]);
                h[2] = (short)f2bf(u0[2]); h[3] = (short)f2bf(u0[3]);
                h[4] = (short)f2bf(u1[0]); h[5] = (short)f2bf(u1[1]);
                h[6] = (short)f2bf(u1[2]); h[7] = (short)f2bf(u1[3]);
                *(short8*)((char*)&As[buf][0] + L) = h;
            }
            const unsigned short* gpB = wbf + (size_t)(bcol + row) * K_DIM + k0 + sc * 8;
            __builtin_amdgcn_global_load_lds(
                (const __attribute__((address_space(1))) unsigned int*)gpB,
                (__attribute__((address_space(3))) unsigned int*)((char*)&Bs[buf][0] + L),
                16, 0, 0);
        }
    };

    f32x4 acc[4][4];
#pragma unroll
    for (int m = 0; m < 4; ++m)
#pragma unroll
        for (int n = 0; n < 4; ++n) acc[m][n] = (f32x4){0.f, 0.f, 0.f, 0.f};

    // Prologue: 3 stages in flight (24 gload_lds/thread in PRECONV).
    stage(0, 0); stage(1, 1); stage(2, 2);

// Ledger (PRECONV, 8 loads/thread/stage): at step KT, stages issued after KT
// = {KT+1..min(5,KT+3)} -> allowed outstanding W = 8*count: 24,24,24,16,8,0.
// Fallback path: vmcnt(0) (ds_write readiness handled by lgkm drains).
#define KSTEP(KT, W, DOSTAGE, DRAIN)                                           \
    {                                                                          \
        if (DOSTAGE) stage((KT + 3) & 3, KT + 3);                              \
        if (PRECONV) { asm volatile("s_waitcnt vmcnt(" #W ")" ::: "memory"); } \
        else         { asm volatile("s_waitcnt vmcnt(0)" ::: "memory"); }      \
        __builtin_amdgcn_s_barrier();                                          \
        _Pragma("unroll")                                                      \
        for (int kk = 0; kk < 2; ++kk) {                                       \
            short8 af[4], bfr[4];                                              \
            _Pragma("unroll")                                                  \
            for (int m = 0; m < 4; ++m) {                                      \
                const int row = wrow + m * 16 + fr;                            \
                const int sc = (kk * 4 + cq) ^ (row & 7);                      \
                af[m] = *(const short8*)((const char*)&As[(KT) & 3][0]         \
                                         + row * 128 + sc * 16);               \
            }                                                                  \
            _Pragma("unroll")                                                  \
            for (int n = 0; n < 4; ++n) {                                      \
                const int row = wcol + n * 16 + fr;                            \
                const int sc = (kk * 4 + cq) ^ (row & 7);                      \
                bfr[n] = *(const short8*)((const char*)&Bs[(KT) & 3][0]        \
                                          + row * 128 + sc * 16);              \
            }                                                                  \
            _Pragma("unroll")                                                  \
            for (int m = 0; m < 4; ++m)                                        \
                _Pragma("unroll")                                              \
                for (int n = 0; n < 4; ++n)                                    \
                    acc[m][n] = __builtin_amdgcn_mfma_f32_16x16x32_bf16(       \
                        af[m], bfr[n], acc[m][n], 0, 0, 0);                    \
        }                                                                      \
        if (DRAIN) {                                                           \
            asm volatile("s_waitcnt lgkmcnt(0)" ::: "memory");                 \
            __builtin_amdgcn_sched_barrier(0);                                 \
            __builtin_amdgcn_s_barrier();                                      \
        }                                                                      \
    }

    KSTEP(0, 24, true,  true)
    KSTEP(1, 24, true,  true)
    KSTEP(2, 24, true,  true)
    KSTEP(3, 16, false, true)
    KSTEP(4, 8,  false, true)
    KSTEP(5, 0,  false, false)
#undef KSTEP

    // ---- epilogue: out = rstd*acc - rm*s1[c] + s2[c], GELU, nt stores ----
    const int cr = ln >> 4;
    float s1c[4], s2c[4];
#pragma unroll
    for (int n = 0; n < 4; ++n) {
        int c = bcol + wcol + n * 16 + fr;
        s1c[n] = s1[c]; s2c[n] = s2[c];
    }
#pragma unroll
    for (int m = 0; m < 4; ++m) {
#pragma unroll
        for (int j = 0; j < 4; ++j) {
            size_t r = brow + wrow + m * 16 + cr * 4 + j;
            float2 st = stats[r];
            float* orow = out + r * N_DIM + bcol + wcol;
#pragma unroll
            for (int n = 0; n < 4; ++n) {
                float val = acc[m][n][j] * st.x - st.y * s1c[n] + s2c[n];
                __builtin_nontemporal_store(gelu_tanh(val), &orow[n * 16 + fr]);
            }
        }
    }
}

extern "C" void kernel_launch(void* const* d_in, const int* in_sizes, int n_in,
                              void* d_out, int out_size, void* d_ws, size_t ws_size,
                              hipStream_t stream) {
    const float* x     = (const float*)d_in[0];
    const float* gamma = (const float*)d_in[1];
    const float* beta  = (const float*)d_in[2];
    const float* W     = (const float*)d_in[3];
    const float* b     = (const float*)d_in[4];
    float* out = (float*)d_out;
    char* ws = (char*)d_ws;

    unsigned short* wbf = (unsigned short*)(ws + OFF_WBF);
    float* s1           = (float*)(ws + OFF_S1);
    float* s2           = (float*)(ws + OFF_S2);
    float2* stats       = (float2*)(ws + OFF_STATS);
    unsigned int* xbf   = (unsigned int*)(ws + OFF_XBF);

    const bool preconv = (ws_size >= WS_FULL);   // constant across calls

    foldW<<<N_DIM / 4, 256, 0, stream>>>(W, gamma, beta, b, wbf, s1, s2);
    lnstats<<<M_DIM / 4, 256, 0, stream>>>(x, stats, xbf, preconv ? 1 : 0);
    if (preconv)
        gemm_ln_gelu<true><<<NBLOCKS, 256, 0, stream>>>(
            (const unsigned short*)xbf, x, wbf, stats, s1, s2, out);
    else
        gemm_ln_gelu<false><<<NBLOCKS, 256, 0, stream>>>(
            (const unsigned short*)xbf, x, wbf, stats, s1, s2, out);
}

// Round 8
// 404.892 us; speedup vs baseline: 1.0862x; 1.0862x over previous
//
#include <hip/hip_runtime.h>

// LayerNorm(384) -> Linear(384->1536) -> exact GELU, fused via:
//   out[m,f] = rstd[m]*dot(x[m], gamma*W[f]) - (mean*rstd)[m]*s1[f] + s2[f]
// R4 (resubmit after broker timeout): depth-2 counted-vmcnt pipeline at 64KB
// LDS (2 blocks/CU): stage(kt+1) issued at top of step kt; mid-step s_waitcnt
// vmcnt(8)+s_barrier (prefetch stays in flight across the barrier);
// end-of-step lgkm-only drain+barrier. T2 XOR-swizzle on LDS tiles
// (inverse-swizzled global source; involution).

#define M_DIM 50176
#define K_DIM 384
#define N_DIM 1536

typedef float f32x4 __attribute__((ext_vector_type(4)));
typedef short short8 __attribute__((ext_vector_type(8)));

#define OFF_WBF   0u
#define OFF_S1    1179648u                  // 1536*384*2
#define OFF_S2    1185792u
#define OFF_STATS 1191936u                  // float2 per row (rstd, mean*rstd)
#define OFF_XBF   1593344u                  // 50176*384 bf16
#define WS_FULL   (OFF_XBF + (size_t)M_DIM * K_DIM * 2)   // ~40.1 MB

__device__ __forceinline__ unsigned short f2bf(float f) {
    unsigned int u = __builtin_bit_cast(unsigned int, f);
    u += 0x7FFFu + ((u >> 16) & 1u);        // RNE
    return (unsigned short)(u >> 16);
}

__device__ __forceinline__ float gelu_tanh(float v) {
    float w = v * v;
    float a = v * (1.5957691f + 0.07135481f * w);
    float e = __expf(-a);
    return v * __builtin_amdgcn_rcpf(1.0f + e);
}

// ---------------- K0: fold gamma into W (bf16) + s1/s2 ----------------
__global__ __launch_bounds__(256) void foldW(
    const float* __restrict__ W, const float* __restrict__ gamma,
    const float* __restrict__ beta, const float* __restrict__ b,
    unsigned short* __restrict__ wbf, float* __restrict__ s1, float* __restrict__ s2)
{
    const int t = threadIdx.x, wv = t >> 6, ln = t & 63;
    const int f = blockIdx.x * 4 + wv;
    const float2* Wr = (const float2*)(W + (size_t)f * K_DIM);
    const float2* g2 = (const float2*)gamma;
    const float2* bt2 = (const float2*)beta;
    float sum1 = 0.f, sum2 = 0.f;
    unsigned int packed[3];
#pragma unroll
    for (int p = 0; p < 3; ++p) {
        int idx = p * 64 + ln;
        float2 w = Wr[idx]; float2 g = g2[idx]; float2 bt = bt2[idx];
        float w0 = w.x * g.x, w1 = w.y * g.y;
        sum1 += w0 + w1;
        sum2 += bt.x * w.x + bt.y * w.y;
        packed[p] = (unsigned int)f2bf(w0) | ((unsigned int)f2bf(w1) << 16);
    }
    unsigned int* wb = (unsigned int*)(wbf + (size_t)f * K_DIM);
#pragma unroll
    for (int p = 0; p < 3; ++p) wb[p * 64 + ln] = packed[p];
#pragma unroll
    for (int off = 32; off >= 1; off >>= 1) {
        sum1 += __shfl_xor(sum1, off);
        sum2 += __shfl_xor(sum2, off);
    }
    if (ln == 0) { s1[f] = sum1; s2[f] = b[f] + sum2; }
}

// ---------------- K1: per-row LN stats (+ optional x->bf16) ----------------
__global__ __launch_bounds__(256) void lnstats(
    const float* __restrict__ x, float2* __restrict__ stats,
    unsigned int* __restrict__ xbf, int do_conv)
{
    const int t = threadIdx.x, wv = t >> 6, ln = t & 63;
    const size_t r = (size_t)blockIdx.x * 4 + wv;
    const float2* xr = (const float2*)(x + r * K_DIM);
    float2 v[3];
    float s = 0.f, sq = 0.f;
#pragma unroll
    for (int p = 0; p < 3; ++p) {
        v[p] = xr[p * 64 + ln];
        s += v[p].x + v[p].y;
        sq += v[p].x * v[p].x + v[p].y * v[p].y;
    }
#pragma unroll
    for (int off = 32; off >= 1; off >>= 1) {
        s += __shfl_xor(s, off);
        sq += __shfl_xor(sq, off);
    }
    float mean = s * (1.0f / 384.0f);
    float var = sq * (1.0f / 384.0f) - mean * mean;
    float rstd = __builtin_amdgcn_rsqf(var + 1e-5f);
    if (ln == 0) stats[r] = make_float2(rstd, mean * rstd);
    if (do_conv) {
        unsigned int* xo = xbf + r * (K_DIM / 2);
#pragma unroll
        for (int p = 0; p < 3; ++p)
            xo[p * 64 + ln] = (unsigned int)f2bf(v[p].x) | ((unsigned int)f2bf(v[p].y) << 16);
    }
}

// ---------------- K2: 128x128 bf16 MFMA GEMM, depth-2 counted-vmcnt ----------
// LDS tile [128 rows][8 chunks of 16B]; LDS chunk cL holds global chunk
// cL^(row&7) (involution). gload_lds dest linear; SOURCE pre-swizzled.
#define NTILE (N_DIM / 128)                 // 12
#define NBLOCKS ((M_DIM / 128) * NTILE)     // 4704
#define KSTEPS (K_DIM / 64)                 // 6

template<bool PRECONV>
__global__ __launch_bounds__(256, 2) void gemm_ln_gelu(
    const unsigned short* __restrict__ xbf, const float* __restrict__ x,
    const unsigned short* __restrict__ wbf, const float2* __restrict__ stats,
    const float* __restrict__ s1, const float* __restrict__ s2,
    float* __restrict__ out)
{
    __shared__ short As[2][128 * 64];       // 2 x 16 KB
    __shared__ short Bs[2][128 * 64];       // 2 x 16 KB  (total 64 KB -> 2 blk/CU)
    const int t = threadIdx.x, wv = t >> 6, ln = t & 63;

    int raw = blockIdx.x;
    int bid = (raw & 7) * (NBLOCKS / 8) + (raw >> 3);   // XCD-chunked, bijective
    int mt = bid / NTILE, ntt = bid % NTILE;
    const size_t brow = (size_t)mt * 128;
    const int bcol = ntt * 128;
    const int wrow = (wv >> 1) * 64, wcol = (wv & 1) * 64;
    const int fr = ln & 15, cq = ln >> 4;   // frag row / 16B-chunk quarter

    auto stage = [&](int buf, int kt) {
        const int k0 = kt * 64;
#pragma unroll
        for (int i = 0; i < 4; ++i) {
            const int L = i * 4096 + t * 16;            // linear byte off in 16KB tile
            const int row = L >> 7;                     // 128B per row
            const int sc  = ((L >> 4) & 7) ^ (row & 7); // source chunk (involution)
            if (PRECONV) {
                const unsigned short* gpA = xbf + (size_t)(brow + row) * K_DIM + k0 + sc * 8;
                __builtin_amdgcn_global_load_lds(
                    (const __attribute__((address_space(1))) unsigned int*)gpA,
                    (__attribute__((address_space(3))) unsigned int*)((char*)&As[buf][0] + L),
                    16, 0, 0);
            } else {
                const float* gp = x + (size_t)(brow + row) * K_DIM + k0 + sc * 8;
                f32x4 u0 = *(const f32x4*)gp;
                f32x4 u1 = *(const f32x4*)(gp + 4);
                short8 h;
                h[0] = (short)f2bf(u0[0]); h[1] = (short)f2bf(u0[1]);
                h[2] = (short)f2bf(u0[2]); h[3] = (short)f2bf(u0[3]);
                h[4] = (short)f2bf(u1[0]); h[5] = (short)f2bf(u1[1]);
                h[6] = (short)f2bf(u1[2]); h[7] = (short)f2bf(u1[3]);
                *(short8*)((char*)&As[buf][0] + L) = h;
            }
            const unsigned short* gpB = wbf + (size_t)(bcol + row) * K_DIM + k0 + sc * 8;
            __builtin_amdgcn_global_load_lds(
                (const __attribute__((address_space(1))) unsigned int*)gpB,
                (__attribute__((address_space(3))) unsigned int*)((char*)&Bs[buf][0] + L),
                16, 0, 0);
        }
    };

    f32x4 acc[4][4];
#pragma unroll
    for (int m = 0; m < 4; ++m)
#pragma unroll
        for (int n = 0; n < 4; ++n) acc[m][n] = (f32x4){0.f, 0.f, 0.f, 0.f};

    stage(0, 0);                            // 8 loads in flight

// Per step kt: issue stage(kt+1) [8 more loads]; wait vmcnt(8) -> stage(kt)
// done while stage(kt+1) flies across the barrier; compute; lgkm-only drain
// + barrier (publishes that buf[kt&1] reads finished; stage(kt+2) at next
// step's top may then overwrite it).  Last step: vmcnt(0), no end barrier.
// Fallback path stages via ds_write + mixed loads -> conservative vmcnt(0).
#define KSTEP(KT, W, DOSTAGE, DRAIN)                                           \
    {                                                                          \
        if (DOSTAGE) stage((KT + 1) & 1, KT + 1);                              \
        if (PRECONV) { asm volatile("s_waitcnt vmcnt(" #W ")" ::: "memory"); } \
        else         { asm volatile("s_waitcnt vmcnt(0)" ::: "memory"); }      \
        __builtin_amdgcn_s_barrier();                                          \
        _Pragma("unroll")                                                      \
        for (int kk = 0; kk < 2; ++kk) {                                       \
            short8 af[4], bfr[4];                                              \
            _Pragma("unroll")                                                  \
            for (int m = 0; m < 4; ++m) {                                      \
                const int row = wrow + m * 16 + fr;                            \
                const int sc = (kk * 4 + cq) ^ (row & 7);                      \
                af[m] = *(const short8*)((const char*)&As[(KT) & 1][0]         \
                                         + row * 128 + sc * 16);               \
            }                                                                  \
            _Pragma("unroll")                                                  \
            for (int n = 0; n < 4; ++n) {                                      \
                const int row = wcol + n * 16 + fr;                            \
                const int sc = (kk * 4 + cq) ^ (row & 7);                      \
                bfr[n] = *(const short8*)((const char*)&Bs[(KT) & 1][0]        \
                                          + row * 128 + sc * 16);              \
            }                                                                  \
            _Pragma("unroll")                                                  \
            for (int m = 0; m < 4; ++m)                                        \
                _Pragma("unroll")                                              \
                for (int n = 0; n < 4; ++n)                                    \
                    acc[m][n] = __builtin_amdgcn_mfma_f32_16x16x32_bf16(       \
                        af[m], bfr[n], acc[m][n], 0, 0, 0);                    \
        }                                                                      \
        if (DRAIN) {                                                           \
            asm volatile("s_waitcnt lgkmcnt(0)" ::: "memory");                 \
            __builtin_amdgcn_sched_barrier(0);                                 \
            __builtin_amdgcn_s_barrier();                                      \
        }                                                                      \
    }

    KSTEP(0, 8, true,  true)
    KSTEP(1, 8, true,  true)
    KSTEP(2, 8, true,  true)
    KSTEP(3, 8, true,  true)
    KSTEP(4, 8, true,  true)
    KSTEP(5, 0, false, false)
#undef KSTEP

    // ---- epilogue: out = rstd*acc - rm*s1[c] + s2[c], GELU, nt stores ----
    const int cr = ln >> 4;
    float s1c[4], s2c[4];
#pragma unroll
    for (int n = 0; n < 4; ++n) {
        int c = bcol + wcol + n * 16 + fr;
        s1c[n] = s1[c]; s2c[n] = s2[c];
    }
#pragma unroll
    for (int m = 0; m < 4; ++m) {
#pragma unroll
        for (int j = 0; j < 4; ++j) {
            size_t r = brow + wrow + m * 16 + cr * 4 + j;
            float2 st = stats[r];
            float* orow = out + r * N_DIM + bcol + wcol;
#pragma unroll
            for (int n = 0; n < 4; ++n) {
                float val = acc[m][n][j] * st.x - st.y * s1c[n] + s2c[n];
                __builtin_nontemporal_store(gelu_tanh(val), &orow[n * 16 + fr]);
            }
        }
    }
}

extern "C" void kernel_launch(void* const* d_in, const int* in_sizes, int n_in,
                              void* d_out, int out_size, void* d_ws, size_t ws_size,
                              hipStream_t stream) {
    const float* x     = (const float*)d_in[0];
    const float* gamma = (const float*)d_in[1];
    const float* beta  = (const float*)d_in[2];
    const float* W     = (const float*)d_in[3];
    const float* b     = (const float*)d_in[4];
    float* out = (float*)d_out;
    char* ws = (char*)d_ws;

    unsigned short* wbf = (unsigned short*)(ws + OFF_WBF);
    float* s1           = (float*)(ws + OFF_S1);
    float* s2           = (float*)(ws + OFF_S2);
    float2* stats       = (float2*)(ws + OFF_STATS);
    unsigned int* xbf   = (unsigned int*)(ws + OFF_XBF);

    const bool preconv = (ws_size >= WS_FULL);   // constant across calls

    foldW<<<N_DIM / 4, 256, 0, stream>>>(W, gamma, beta, b, wbf, s1, s2);
    lnstats<<<M_DIM / 4, 256, 0, stream>>>(x, stats, xbf, preconv ? 1 : 0);
    if (preconv)
        gemm_ln_gelu<true><<<NBLOCKS, 256, 0, stream>>>(
            (const unsigned short*)xbf, x, wbf, stats, s1, s2, out);
    else
        gemm_ln_gelu<false><<<NBLOCKS, 256, 0, stream>>>(
            (const unsigned short*)xbf, x, wbf, stats, s1, s2, out);
}